// Round 5
// baseline (5470.088 us; speedup 1.0000x reference)
//
#include <hip/hip_runtime.h>
#include <hip/hip_fp16.h>

#define DD 1024
#define TSTEPS 1024
#define BATCH 8
#define NWG 64
#define ROWS 16
#define HFS 1028   // LDS hf row stride in halves (514 dwords, 514%32=2 -> conflict-free-ish)

typedef _Float16 half8 __attribute__((ext_vector_type(8)));
typedef float floatx4 __attribute__((ext_vector_type(4)));

// ---- d_out float offsets ----
#define OUT_OFF   0
#define LOGH_OFF  8388608
#define SIGNH_OFF 16785408
#define HLIN_OFF  25182208

// ---- ws byte offsets ----
#define WS_SCALES  0          // float[2]
#define WS_SUMSQ   64         // float[2][8]
#define WS_FLAGS   128        // int[64] monotonic HINT flags -> [128,384)
#define WS_CNTS    384        // int[2][8] spectral barriers -> [384,448)
#define WS_SPECVEC 512        // float[2][2][1024] power-iter ping-pong -> [512,16896)
#define WS_COMM    16896      // unsigned[2][8][1024] tagged payload -> [16896,82432)
// comm dword = ((t+1)<<16) | f16(h): data + readiness land atomically in ONE
// dword store -> tags are the correctness authority; NO producer vmcnt ack
// anywhere. flags[] are fire-and-forget HINTS that gate the (single) bulk
// read -- no speculative sweeps (round-4 lesson: they always miss in the
// phase-locked steady state). Zeroed each launch (stale tags would alias).

__device__ __forceinline__ int aload_i(int* p) { return __hip_atomic_load(p, __ATOMIC_RELAXED, __HIP_MEMORY_SCOPE_AGENT); }
__device__ __forceinline__ float aload_f(float* p) { return __hip_atomic_load(p, __ATOMIC_RELAXED, __HIP_MEMORY_SCOPE_AGENT); }
__device__ __forceinline__ unsigned aload_u(unsigned* p) { return __hip_atomic_load(p, __ATOMIC_RELAXED, __HIP_MEMORY_SCOPE_AGENT); }
__device__ __forceinline__ void astore_f(float* p, float v) { __hip_atomic_store(p, v, __ATOMIC_RELAXED, __HIP_MEMORY_SCOPE_AGENT); }
__device__ __forceinline__ void astore_i(int* p, int v) { __hip_atomic_store(p, v, __ATOMIC_RELAXED, __HIP_MEMORY_SCOPE_AGENT); }
__device__ __forceinline__ void astore_u(unsigned* p, unsigned v) { __hip_atomic_store(p, v, __ATOMIC_RELAXED, __HIP_MEMORY_SCOPE_AGENT); }
__device__ __forceinline__ void aadd_i(int* p, int v) { (void)__hip_atomic_fetch_add(p, v, __ATOMIC_RELAXED, __HIP_MEMORY_SCOPE_AGENT); }
__device__ __forceinline__ void waitcnt_vm0() { asm volatile("s_waitcnt vmcnt(0)" ::: "memory"); }

// ============================================================================
// Spectral norm: 3-step power iteration for both matrices concurrently.
// ============================================================================
__global__ __launch_bounds__(256) void spectral_kernel(
    const float* __restrict__ Wh, const float* __restrict__ Wd,
    const float* __restrict__ uh, const float* __restrict__ ud,
    unsigned char* __restrict__ ws) {
  const int g  = blockIdx.x >> 6;
  const int wg = blockIdx.x & 63;
  const int tid = threadIdx.x;
  const float* W  = g ? Wd : Wh;
  const float* u0 = g ? ud : uh;
  float* scales = (float*)(ws + WS_SCALES);
  float* sumsq  = (float*)(ws + WS_SUMSQ) + g*8;
  int*   cnt    = (int*)(ws + WS_CNTS) + g*8;
  float* ubuf   = (float*)(ws + WS_SPECVEC) + g*2048;
  float* vbuf   = ubuf + 1024;

  __shared__ float xs[1024];
  __shared__ float tileW[256*17];
  __shared__ float red[16*17];

  float ss = 0.f;
  for (int i2 = tid; i2 < 1024; i2 += 256) { float x = u0[i2]; ss += x*x; }
  #pragma unroll
  for (int off = 1; off < 64; off <<= 1) ss += __shfl_xor(ss, off);
  if ((tid & 63) == 0) red[tid >> 6] = ss;
  __syncthreads();
  float inv_prev = 1.f/(sqrtf(red[0]+red[1]+red[2]+red[3]) + 1e-8f);
  __syncthreads();

  for (int p = 1; p <= 6; ++p) {
    const int colmv = p & 1;
    float* dst  = colmv ? vbuf : ubuf;
    float* srcw = colmv ? ubuf : vbuf;
    float part = 0.f;
    if (colmv) {
      const int jb = wg*16;
      const int jl = tid & 15, is = tid >> 4;
      float acc = 0.f;
      for (int i0 = 0; i0 < 1024; i0 += 256) {
        __syncthreads();
        float xv = (p == 1) ? u0[i0 + tid] : aload_f(srcw + i0 + tid);
        xs[tid] = xv * inv_prev;
        const float* wr = W + (size_t)(i0 + tid)*DD + jb;
        float4 a = *(const float4*)(wr + 0);
        float4 bq = *(const float4*)(wr + 4);
        float4 cq = *(const float4*)(wr + 8);
        float4 dq = *(const float4*)(wr + 12);
        float* tr = tileW + tid*17;
        tr[0]=a.x; tr[1]=a.y; tr[2]=a.z; tr[3]=a.w;
        tr[4]=bq.x; tr[5]=bq.y; tr[6]=bq.z; tr[7]=bq.w;
        tr[8]=cq.x; tr[9]=cq.y; tr[10]=cq.z; tr[11]=cq.w;
        tr[12]=dq.x; tr[13]=dq.y; tr[14]=dq.z; tr[15]=dq.w;
        __syncthreads();
        #pragma unroll 4
        for (int ii = 0; ii < 16; ++ii)
          acc += tileW[(is*16 + ii)*17 + jl] * xs[is*16 + ii];
      }
      __syncthreads();
      red[is*17 + jl] = acc;
      __syncthreads();
      if (tid < 16) {
        float y = 0.f;
        #pragma unroll
        for (int k = 0; k < 16; ++k) y += red[k*17 + tid];
        astore_f(dst + jb + tid, y);
        part = y*y;
      }
    } else {
      const int ib = wg*16;
      for (int i2 = tid; i2 < 1024; i2 += 256) xs[i2] = aload_f(srcw + i2) * inv_prev;
      __syncthreads();
      const int r = tid >> 4, s = tid & 15;
      const float* wr = W + (size_t)(ib + r)*DD;
      float acc = 0.f;
      #pragma unroll 8
      for (int jj = 0; jj < 64; ++jj) {
        int j = s + (jj << 4);
        acc += wr[j] * xs[j];
      }
      #pragma unroll
      for (int off = 1; off < 16; off <<= 1) acc += __shfl_xor(acc, off);
      __syncthreads();
      if (s == 0) red[r] = acc;
      __syncthreads();
      if (tid < 16) {
        float y = red[tid];
        astore_f(dst + ib + tid, y);
        part = y*y;
      }
    }
    #pragma unroll
    for (int off = 1; off < 16; off <<= 1) part += __shfl_xor(part, off);
    if (tid == 0) atomicAdd(sumsq + p, part);
    waitcnt_vm0();
    __syncthreads();
    if (tid == 0) {
      aadd_i(cnt + p, 1);
      while (aload_i(cnt + p) < 64) __builtin_amdgcn_s_sleep(1);
    }
    __syncthreads();
    float stot = aload_f(sumsq + p);
    inv_prev = 1.f/(sqrtf(stot) + 1e-8f);
    __syncthreads();
  }
  if (wg == 0 && tid == 0) {
    float n2 = aload_f(sumsq + 6);
    float nn = sqrtf(n2);
    float sigma = (nn*nn)/(nn + 1e-8f);
    scales[g] = 0.99f/(sigma + 1e-8f);
  }
}

// ============================================================================
// f16 MFMA GEMM (dual-B variant shares the A tile). M=8192, N=K=1024.
// ============================================================================
__device__ __forceinline__ half8 cvt8(const float* p) {
  float4 lo = *(const float4*)p;
  float4 hi = *(const float4*)(p+4);
  half8 h;
  h[0]=(_Float16)lo.x; h[1]=(_Float16)lo.y; h[2]=(_Float16)lo.z; h[3]=(_Float16)lo.w;
  h[4]=(_Float16)hi.x; h[5]=(_Float16)hi.y; h[6]=(_Float16)hi.z; h[7]=(_Float16)hi.w;
  return h;
}

__global__ __launch_bounds__(256) void gemm_f16(
    const float* __restrict__ A,
    const float* __restrict__ B1, const float* __restrict__ B2,
    const float* __restrict__ bias1, const float* __restrict__ bias2,
    float* __restrict__ C1, float* __restrict__ C2) {
  const int n0 = blockIdx.x * 64;
  const int m0 = blockIdx.y * 64;
  const int tid = threadIdx.x;
  const int wave = tid >> 6, lane = tid & 63;
  const int quad = lane >> 4, l16 = lane & 15;
  const bool dual = (B2 != nullptr);
  __shared__ _Float16 As[64*40];
  __shared__ _Float16 Bs1[64*40];
  __shared__ _Float16 Bs2[64*40];
  floatx4 zero = {0.f,0.f,0.f,0.f};
  floatx4 acc1[2][2] = {{zero,zero},{zero,zero}};
  floatx4 acc2[2][2] = {{zero,zero},{zero,zero}};
  const int srow = tid >> 2;
  const int sseg = (tid & 3) * 8;
  const int mb = (wave >> 1)*32, nb = (wave & 1)*32;
  for (int k0 = 0; k0 < 1024; k0 += 32) {
    __syncthreads();
    *(half8*)&As[srow*40 + sseg]  = cvt8(A  + (size_t)(m0+srow)*DD + k0 + sseg);
    *(half8*)&Bs1[srow*40 + sseg] = cvt8(B1 + (size_t)(n0+srow)*DD + k0 + sseg);
    if (dual) *(half8*)&Bs2[srow*40 + sseg] = cvt8(B2 + (size_t)(n0+srow)*DD + k0 + sseg);
    __syncthreads();
    half8 a0 = *(const half8*)&As[(mb + l16)*40 + quad*8];
    half8 a1 = *(const half8*)&As[(mb + 16 + l16)*40 + quad*8];
    half8 b0 = *(const half8*)&Bs1[(nb + l16)*40 + quad*8];
    half8 b1 = *(const half8*)&Bs1[(nb + 16 + l16)*40 + quad*8];
    acc1[0][0] = __builtin_amdgcn_mfma_f32_16x16x32_f16(a0, b0, acc1[0][0], 0,0,0);
    acc1[0][1] = __builtin_amdgcn_mfma_f32_16x16x32_f16(a0, b1, acc1[0][1], 0,0,0);
    acc1[1][0] = __builtin_amdgcn_mfma_f32_16x16x32_f16(a1, b0, acc1[1][0], 0,0,0);
    acc1[1][1] = __builtin_amdgcn_mfma_f32_16x16x32_f16(a1, b1, acc1[1][1], 0,0,0);
    if (dual) {
      half8 c0 = *(const half8*)&Bs2[(nb + l16)*40 + quad*8];
      half8 c1 = *(const half8*)&Bs2[(nb + 16 + l16)*40 + quad*8];
      acc2[0][0] = __builtin_amdgcn_mfma_f32_16x16x32_f16(a0, c0, acc2[0][0], 0,0,0);
      acc2[0][1] = __builtin_amdgcn_mfma_f32_16x16x32_f16(a0, c1, acc2[0][1], 0,0,0);
      acc2[1][0] = __builtin_amdgcn_mfma_f32_16x16x32_f16(a1, c0, acc2[1][0], 0,0,0);
      acc2[1][1] = __builtin_amdgcn_mfma_f32_16x16x32_f16(a1, c1, acc2[1][1], 0,0,0);
    }
  }
  #pragma unroll
  for (int in = 0; in < 2; ++in) {
    const int n = n0 + nb + in*16 + l16;
    const float bv1 = bias1 ? bias1[n] : 0.f;
    const float bv2 = (dual && bias2) ? bias2[n] : 0.f;
    #pragma unroll
    for (int im = 0; im < 2; ++im) {
      const int mrow = m0 + mb + im*16 + quad*4;
      floatx4 c = acc1[im][in];
      #pragma unroll
      for (int r2 = 0; r2 < 4; ++r2) C1[(size_t)(mrow + r2)*DD + n] = c[r2] + bv1;
      if (dual) {
        floatx4 c2 = acc2[im][in];
        #pragma unroll
        for (int r2 = 0; r2 < 4; ++r2) C2[(size_t)(mrow + r2)*DD + n] = c2[r2] + bv2;
      }
    }
  }
}

// ============================================================================
// Persistent recurrence: tagged payload (authority) + hint flags (detector),
// NO producer ack. Producer: ep-threads fire-and-forget tagged dwords; each
// wave's lane-0 fires the hint flag right after its own payload store (no
// vmcnt(0) -- the round-2 ack RTT is deleted from the critical path).
// Consumer: flag-poll (cheap, 256B) -> ONE batched 32-load tagged read ->
// rare retry of pending dwords with s_sleep backoff. No speculative sweeps
// (round-4 lesson: they always miss under phase lock).
// ============================================================================
__global__ __launch_bounds__(256, 1) void recurrence_kernel(
    const float* __restrict__ Rh_raw, const float* __restrict__ Rd_raw,
    const float* __restrict__ logh0, const float* __restrict__ signh0,
    float* __restrict__ dout, unsigned char* __restrict__ ws) {
  const int wg = blockIdx.x;
  const int i0 = wg * ROWS;
  const int tid = threadIdx.x;
  const int wave = tid >> 6, lane = tid & 63;
  const int quad = lane >> 4, l16 = lane & 15;

  float* out_ax = dout + OUT_OFF;     // ax aliased into 'out' region
  float* hlin   = dout + HLIN_OFF;    // ad aliased here (consumed per step)
  float* logh   = dout + LOGH_OFF;
  float* signh  = dout + SIGNH_OFF;
  const float* scales = (const float*)(ws + WS_SCALES);
  unsigned* comm = (unsigned*)(ws + WS_COMM);   // dwords: [2][8][1024] = [buf][b][row]
  int* flags = (int*)(ws + WS_FLAGS);           // int[64], monotonic HINTS

  __shared__ _Float16 hf[16*HFS];
  __shared__ floatx4 scr_v[4][64];
  __shared__ floatx4 scr_d[4][64];

  // zero pad batch rows 8..15 of hf (never re-written)
  for (int idx = tid; idx < 8*HFS; idx += 256) hf[8*HFS + idx] = (_Float16)0.f;

  // static A-fragments: weights * spectral scale, f16. A[m=l16][k=quad*8+j].
  const float sh = scales[0], sd = scales[1];
  half8 afv[8], afd[8];
  {
    const float* rv = Rh_raw + (size_t)(i0 + l16)*DD;
    const float* rd = Rd_raw + (size_t)(i0 + l16)*DD;
    for (int ks = 0; ks < 8; ++ks) {
      const int kb = wave*256 + ks*32 + quad*8;
      half8 hv, hd;
      #pragma unroll
      for (int j = 0; j < 8; ++j) {
        hv[j] = (_Float16)(rv[kb + j] * sh);
        hd[j] = (_Float16)(rd[kb + j] * sd);
      }
      afv[ks] = hv; afd[ks] = hd;
    }
  }

  // epilogue identity: tid<128 -> (row em, batch eb)
  const int em = tid & 15;
  const int eb = tid >> 4;
  const bool ep = (tid < 128);
  const int ei = i0 + em;
  float hp = 0.f;
  if (ep) hp = signh0[eb*DD + ei] * expf(logh0[eb*DD + ei]);

  __syncthreads();

  for (int t = 0; t < TSTEPS; ++t) {
    // prefetch ax/ad (HBM latency hidden under the poll)
    float axv = 0.f, adv = 0.f;
    if (ep) {
      axv = out_ax[(size_t)(t*8 + eb)*DD + ei];
      adv = hlin[(size_t)(t*8 + eb)*DD + ei];   // ad aliased; overwritten below
    }
    float vsum = 0.f, dsum = 0.f;
    if (t > 0) {
      // phase 1a: hint-flag poll (all waves; one coalesced 256B load/round)
      {
        unsigned long long mask;
        do {
          int fv = aload_i(flags + lane);
          mask = __ballot(fv >= t);
        } while (mask != ~0ull);
      }
      // phase 1b: ONE batched tagged read of buffer[(t-1)&1]; expected tag t.
      // Payload was stored before the flag on each producer, so pending
      // dwords are rare; retry only those, with backoff.
      unsigned* src = comm + ((t-1)&1)*8192 + tid;
      const unsigned tagw = (unsigned)t;
      unsigned rbuf[32];
      unsigned pend;
      {
        #pragma unroll
        for (int q = 0; q < 32; ++q) rbuf[q] = aload_u(src + q*256);
        unsigned np = 0u;
        #pragma unroll
        for (int q = 0; q < 32; ++q) np |= ((rbuf[q] >> 16) != tagw) ? (1u << q) : 0u;
        pend = np;
      }
      while (__any(pend != 0u)) {
        __builtin_amdgcn_s_sleep(1);
        unsigned tmp[32];
        #pragma unroll
        for (int q = 0; q < 32; ++q) if (pend & (1u << q)) tmp[q] = aload_u(src + q*256);
        unsigned np = 0u;
        #pragma unroll
        for (int q = 0; q < 32; ++q) if (pend & (1u << q)) {
          rbuf[q] = tmp[q];
          np |= ((tmp[q] >> 16) != tagw) ? (1u << q) : 0u;
        }
        pend = np;
      }
      // phase 2: registers -> LDS (2-way half writes = conflict-free)
      #pragma unroll
      for (int q = 0; q < 32; ++q) {
        const int w = q*256 + tid;
        *(unsigned short*)&hf[(w >> 10)*HFS + (w & 1023)] = (unsigned short)(rbuf[q] & 0xffffu);
      }
      __syncthreads();
      // phase 3: MFMA over this wave's K-slice (both matrices share B-frag)
      floatx4 av = {0.f,0.f,0.f,0.f}, ad2 = {0.f,0.f,0.f,0.f};
      const int kw = wave*256;
      #pragma unroll
      for (int ks = 0; ks < 8; ++ks) {
        half8 bfrag = *(const half8*)&hf[l16*HFS + kw + ks*32 + quad*8];
        av  = __builtin_amdgcn_mfma_f32_16x16x32_f16(afv[ks], bfrag, av,  0, 0, 0);
        ad2 = __builtin_amdgcn_mfma_f32_16x16x32_f16(afd[ks], bfrag, ad2, 0, 0, 0);
      }
      scr_v[wave][lane] = av;
      scr_d[wave][lane] = ad2;
      __syncthreads();
      if (ep) {
        // C[m][n]: lane=(m>>2)*16+n, reg=m&3
        const int rl = ((em >> 2) << 4) + eb;
        const int rr = em & 3;
        #pragma unroll
        for (int w2 = 0; w2 < 4; ++w2) {
          vsum += scr_v[w2][rl][rr];
          dsum += scr_d[w2][rl][rr];
        }
      }
    }
    // phase 4: epilogue; publish tagged dword immediately, then hint flag
    // (both fire-and-forget, NO ack), then off-critical-path output stores.
    if (ep) {
      float v  = axv + vsum;
      float dd = adv + dsum;
      float cand  = tanhf(v);
      float delta = 1.f/(1.f + expf(-dd));
      float hn = (1.f - delta)*hp + delta*cand;
      hp = hn;
      unsigned pd = ((unsigned)(t + 1) << 16) |
                    (unsigned)__half_as_ushort(__float2half(hn));
      astore_u(comm + (t & 1)*8192 + eb*1024 + ei, pd);
      if ((tid & 63) == 0) astore_i(flags + wg, t + 1);   // hint, unacked
      float logv = logf(fabsf(hn) + 1e-12f);
      float sgn = (hn >= 0.f) ? 1.f : -1.f;
      const size_t oidx = (size_t)(t*8 + eb)*DD + ei;
      hlin[oidx] = hn;
      logh[(size_t)((t+1)*8 + eb)*DD + ei] = logv;
      signh[(size_t)((t+1)*8 + eb)*DD + ei] = sgn;
    }
  }
}

// ============================================================================
// out = softmax(h over groups of 32) * silu(h @ W_out^T), element-wise rewrite.
// ============================================================================
__global__ __launch_bounds__(256) void out_epilogue(
    const float* __restrict__ hlin, float* __restrict__ y_out) {
  const int row = blockIdx.x;          // t*8+b
  const int tid = threadIdx.x;
  const float* h = hlin + (size_t)row*DD;
  float* yo = y_out + (size_t)row*DD;
  const int e = tid*4;
  float4 hv = *(const float4*)(h + e);
  float4 yv = *(const float4*)(yo + e);
  float m = fmaxf(fmaxf(hv.x,hv.y), fmaxf(hv.z,hv.w));
  #pragma unroll
  for (int off = 1; off < 8; off <<= 1) m = fmaxf(m, __shfl_xor(m, off));
  float e0 = expf(hv.x - m), e1 = expf(hv.y - m), e2 = expf(hv.z - m), e3 = expf(hv.w - m);
  float s = e0+e1+e2+e3;
  #pragma unroll
  for (int off = 1; off < 8; off <<= 1) s += __shfl_xor(s, off);
  float inv = 1.f/s;
  float4 o;
  o.x = e0*inv * (yv.x/(1.f+expf(-yv.x)));
  o.y = e1*inv * (yv.y/(1.f+expf(-yv.y)));
  o.z = e2*inv * (yv.z/(1.f+expf(-yv.z)));
  o.w = e3*inv * (yv.w/(1.f+expf(-yv.w)));
  *(float4*)(yo + e) = o;
}

__global__ __launch_bounds__(256) void init_rows(
    const float* __restrict__ lh0, const float* __restrict__ sh0, float* __restrict__ dout) {
  int idx = blockIdx.x*256 + threadIdx.x;   // 8192
  dout[LOGH_OFF + idx]  = lh0[idx];
  dout[SIGNH_OFF + idx] = sh0[idx];
}

extern "C" void kernel_launch(void* const* d_in, const int* in_sizes, int n_in,
                              void* d_out, int out_size, void* d_ws, size_t ws_size,
                              hipStream_t stream) {
  const float* x      = (const float*)d_in[0];
  const float* logh0  = (const float*)d_in[1];
  const float* signh0 = (const float*)d_in[2];
  const float* Rh_raw = (const float*)d_in[3];
  const float* Rx     = (const float*)d_in[4];
  const float* Rd_raw = (const float*)d_in[5];
  const float* Wdelta = (const float*)d_in[6];
  const float* Wout   = (const float*)d_in[7];
  const float* bvec   = (const float*)d_in[8];
  const float* bdelta = (const float*)d_in[9];
  const float* uh     = (const float*)d_in[10];
  const float* ud     = (const float*)d_in[11];
  float* out = (float*)d_out;
  unsigned char* ws = (unsigned char*)d_ws;

  // zero scales/sumsq/flags/cnts AND the tagged comm region (stale tags from
  // a previous replay would alias with this run's step tags)
  hipMemsetAsync(ws, 0, WS_COMM + 2*8192*4, stream);
  spectral_kernel<<<128, 256, 0, stream>>>(Rh_raw, Rd_raw, uh, ud, ws);
  // ax -> out region, ad -> h_lin region (dead-aliased scratch)
  gemm_f16<<<dim3(16,128), 256, 0, stream>>>(x, Rx, Wdelta, bvec, bdelta,
                                             out + OUT_OFF, out + HLIN_OFF);
  init_rows<<<32, 256, 0, stream>>>(logh0, signh0, out);
  recurrence_kernel<<<NWG, 256, 0, stream>>>(Rh_raw, Rd_raw, logh0, signh0, out, ws);
  // Y = h_lin @ W_out^T -> out region (ax dead)
  gemm_f16<<<dim3(16,128), 256, 0, stream>>>(out + HLIN_OFF, Wout, nullptr, nullptr, nullptr,
                                             out + OUT_OFF, nullptr);
  out_epilogue<<<8192, 256, 0, stream>>>(out + HLIN_OFF, out + OUT_OFF);
}

// Round 6
// 4637.051 us; speedup vs baseline: 1.1796x; 1.1796x over previous
//
#include <hip/hip_runtime.h>
#include <hip/hip_fp16.h>

#define DD 1024
#define TSTEPS 1024
#define BATCH 8
#define NWG 16
#define ROWS 64
#define HFS 1028   // LDS hf row stride in halves (514 dwords, 514%32=2 -> conflict-free-ish)

typedef _Float16 half8 __attribute__((ext_vector_type(8)));
typedef float floatx4 __attribute__((ext_vector_type(4)));

// ---- d_out float offsets ----
#define OUT_OFF   0
#define LOGH_OFF  8388608
#define SIGNH_OFF 16785408
#define HLIN_OFF  25182208

// ---- ws byte offsets ----
#define WS_SCALES  0          // float[2]
#define WS_SUMSQ   64         // float[2][8]
#define WS_FLAGS   128        // int[64] = [16 WG][4 wave] monotonic flags -> [128,384)
#define WS_CNTS    384        // int[2][8] spectral barriers -> [384,448)
#define WS_SPECVEC 512        // float[2][2][1024] power-iter ping-pong -> [512,16896)
#define WS_COMM    16896      // ushort[2][8][1024] packed f16 h double-buffer -> [16896,49664)
// Protocol = round-2's (proven hop-minimal over rounds 3-5): per-wave payload
// stores -> per-wave vmcnt(0) ack -> per-wave flag. Consumer: poll 64 flags,
// then ONE batched 16-load payload read (visibility certified by the ack).

__device__ __forceinline__ int aload_i(int* p) { return __hip_atomic_load(p, __ATOMIC_RELAXED, __HIP_MEMORY_SCOPE_AGENT); }
__device__ __forceinline__ float aload_f(float* p) { return __hip_atomic_load(p, __ATOMIC_RELAXED, __HIP_MEMORY_SCOPE_AGENT); }
__device__ __forceinline__ unsigned aload_u(unsigned* p) { return __hip_atomic_load(p, __ATOMIC_RELAXED, __HIP_MEMORY_SCOPE_AGENT); }
__device__ __forceinline__ void astore_f(float* p, float v) { __hip_atomic_store(p, v, __ATOMIC_RELAXED, __HIP_MEMORY_SCOPE_AGENT); }
__device__ __forceinline__ void astore_i(int* p, int v) { __hip_atomic_store(p, v, __ATOMIC_RELAXED, __HIP_MEMORY_SCOPE_AGENT); }
__device__ __forceinline__ void astore_u64(unsigned long long* p, unsigned long long v) { __hip_atomic_store(p, v, __ATOMIC_RELAXED, __HIP_MEMORY_SCOPE_AGENT); }
__device__ __forceinline__ void aadd_i(int* p, int v) { (void)__hip_atomic_fetch_add(p, v, __ATOMIC_RELAXED, __HIP_MEMORY_SCOPE_AGENT); }
__device__ __forceinline__ void waitcnt_vm0() { asm volatile("s_waitcnt vmcnt(0)" ::: "memory"); }

// ============================================================================
// Spectral norm: 3-step power iteration for both matrices concurrently.
// ============================================================================
__global__ __launch_bounds__(256) void spectral_kernel(
    const float* __restrict__ Wh, const float* __restrict__ Wd,
    const float* __restrict__ uh, const float* __restrict__ ud,
    unsigned char* __restrict__ ws) {
  const int g  = blockIdx.x >> 6;
  const int wg = blockIdx.x & 63;
  const int tid = threadIdx.x;
  const float* W  = g ? Wd : Wh;
  const float* u0 = g ? ud : uh;
  float* scales = (float*)(ws + WS_SCALES);
  float* sumsq  = (float*)(ws + WS_SUMSQ) + g*8;
  int*   cnt    = (int*)(ws + WS_CNTS) + g*8;
  float* ubuf   = (float*)(ws + WS_SPECVEC) + g*2048;
  float* vbuf   = ubuf + 1024;

  __shared__ float xs[1024];
  __shared__ float tileW[256*17];
  __shared__ float red[16*17];

  float ss = 0.f;
  for (int i2 = tid; i2 < 1024; i2 += 256) { float x = u0[i2]; ss += x*x; }
  #pragma unroll
  for (int off = 1; off < 64; off <<= 1) ss += __shfl_xor(ss, off);
  if ((tid & 63) == 0) red[tid >> 6] = ss;
  __syncthreads();
  float inv_prev = 1.f/(sqrtf(red[0]+red[1]+red[2]+red[3]) + 1e-8f);
  __syncthreads();

  for (int p = 1; p <= 6; ++p) {
    const int colmv = p & 1;
    float* dst  = colmv ? vbuf : ubuf;
    float* srcw = colmv ? ubuf : vbuf;
    float part = 0.f;
    if (colmv) {
      const int jb = wg*16;
      const int jl = tid & 15, is = tid >> 4;
      float acc = 0.f;
      for (int i0 = 0; i0 < 1024; i0 += 256) {
        __syncthreads();
        float xv = (p == 1) ? u0[i0 + tid] : aload_f(srcw + i0 + tid);
        xs[tid] = xv * inv_prev;
        const float* wr = W + (size_t)(i0 + tid)*DD + jb;
        float4 a = *(const float4*)(wr + 0);
        float4 bq = *(const float4*)(wr + 4);
        float4 cq = *(const float4*)(wr + 8);
        float4 dq = *(const float4*)(wr + 12);
        float* tr = tileW + tid*17;
        tr[0]=a.x; tr[1]=a.y; tr[2]=a.z; tr[3]=a.w;
        tr[4]=bq.x; tr[5]=bq.y; tr[6]=bq.z; tr[7]=bq.w;
        tr[8]=cq.x; tr[9]=cq.y; tr[10]=cq.z; tr[11]=cq.w;
        tr[12]=dq.x; tr[13]=dq.y; tr[14]=dq.z; tr[15]=dq.w;
        __syncthreads();
        #pragma unroll 4
        for (int ii = 0; ii < 16; ++ii)
          acc += tileW[(is*16 + ii)*17 + jl] * xs[is*16 + ii];
      }
      __syncthreads();
      red[is*17 + jl] = acc;
      __syncthreads();
      if (tid < 16) {
        float y = 0.f;
        #pragma unroll
        for (int k = 0; k < 16; ++k) y += red[k*17 + tid];
        astore_f(dst + jb + tid, y);
        part = y*y;
      }
    } else {
      const int ib = wg*16;
      for (int i2 = tid; i2 < 1024; i2 += 256) xs[i2] = aload_f(srcw + i2) * inv_prev;
      __syncthreads();
      const int r = tid >> 4, s = tid & 15;
      const float* wr = W + (size_t)(ib + r)*DD;
      float acc = 0.f;
      #pragma unroll 8
      for (int jj = 0; jj < 64; ++jj) {
        int j = s + (jj << 4);
        acc += wr[j] * xs[j];
      }
      #pragma unroll
      for (int off = 1; off < 16; off <<= 1) acc += __shfl_xor(acc, off);
      __syncthreads();
      if (s == 0) red[r] = acc;
      __syncthreads();
      if (tid < 16) {
        float y = red[tid];
        astore_f(dst + ib + tid, y);
        part = y*y;
      }
    }
    #pragma unroll
    for (int off = 1; off < 16; off <<= 1) part += __shfl_xor(part, off);
    if (tid == 0) atomicAdd(sumsq + p, part);
    waitcnt_vm0();
    __syncthreads();
    if (tid == 0) {
      aadd_i(cnt + p, 1);
      while (aload_i(cnt + p) < 64) __builtin_amdgcn_s_sleep(1);
    }
    __syncthreads();
    float stot = aload_f(sumsq + p);
    inv_prev = 1.f/(sqrtf(stot) + 1e-8f);
    __syncthreads();
  }
  if (wg == 0 && tid == 0) {
    float n2 = aload_f(sumsq + 6);
    float nn = sqrtf(n2);
    float sigma = (nn*nn)/(nn + 1e-8f);
    scales[g] = 0.99f/(sigma + 1e-8f);
  }
}

// ============================================================================
// f16 MFMA GEMM (dual-B variant shares the A tile). M=8192, N=K=1024.
// ============================================================================
__device__ __forceinline__ half8 cvt8(const float* p) {
  float4 lo = *(const float4*)p;
  float4 hi = *(const float4*)(p+4);
  half8 h;
  h[0]=(_Float16)lo.x; h[1]=(_Float16)lo.y; h[2]=(_Float16)lo.z; h[3]=(_Float16)lo.w;
  h[4]=(_Float16)hi.x; h[5]=(_Float16)hi.y; h[6]=(_Float16)hi.z; h[7]=(_Float16)hi.w;
  return h;
}

__global__ __launch_bounds__(256) void gemm_f16(
    const float* __restrict__ A,
    const float* __restrict__ B1, const float* __restrict__ B2,
    const float* __restrict__ bias1, const float* __restrict__ bias2,
    float* __restrict__ C1, float* __restrict__ C2) {
  const int n0 = blockIdx.x * 64;
  const int m0 = blockIdx.y * 64;
  const int tid = threadIdx.x;
  const int wave = tid >> 6, lane = tid & 63;
  const int quad = lane >> 4, l16 = lane & 15;
  const bool dual = (B2 != nullptr);
  __shared__ _Float16 As[64*40];
  __shared__ _Float16 Bs1[64*40];
  __shared__ _Float16 Bs2[64*40];
  floatx4 zero = {0.f,0.f,0.f,0.f};
  floatx4 acc1[2][2] = {{zero,zero},{zero,zero}};
  floatx4 acc2[2][2] = {{zero,zero},{zero,zero}};
  const int srow = tid >> 2;
  const int sseg = (tid & 3) * 8;
  const int mb = (wave >> 1)*32, nb = (wave & 1)*32;
  for (int k0 = 0; k0 < 1024; k0 += 32) {
    __syncthreads();
    *(half8*)&As[srow*40 + sseg]  = cvt8(A  + (size_t)(m0+srow)*DD + k0 + sseg);
    *(half8*)&Bs1[srow*40 + sseg] = cvt8(B1 + (size_t)(n0+srow)*DD + k0 + sseg);
    if (dual) *(half8*)&Bs2[srow*40 + sseg] = cvt8(B2 + (size_t)(n0+srow)*DD + k0 + sseg);
    __syncthreads();
    half8 a0 = *(const half8*)&As[(mb + l16)*40 + quad*8];
    half8 a1 = *(const half8*)&As[(mb + 16 + l16)*40 + quad*8];
    half8 b0 = *(const half8*)&Bs1[(nb + l16)*40 + quad*8];
    half8 b1 = *(const half8*)&Bs1[(nb + 16 + l16)*40 + quad*8];
    acc1[0][0] = __builtin_amdgcn_mfma_f32_16x16x32_f16(a0, b0, acc1[0][0], 0,0,0);
    acc1[0][1] = __builtin_amdgcn_mfma_f32_16x16x32_f16(a0, b1, acc1[0][1], 0,0,0);
    acc1[1][0] = __builtin_amdgcn_mfma_f32_16x16x32_f16(a1, b0, acc1[1][0], 0,0,0);
    acc1[1][1] = __builtin_amdgcn_mfma_f32_16x16x32_f16(a1, b1, acc1[1][1], 0,0,0);
    if (dual) {
      half8 c0 = *(const half8*)&Bs2[(nb + l16)*40 + quad*8];
      half8 c1 = *(const half8*)&Bs2[(nb + 16 + l16)*40 + quad*8];
      acc2[0][0] = __builtin_amdgcn_mfma_f32_16x16x32_f16(a0, c0, acc2[0][0], 0,0,0);
      acc2[0][1] = __builtin_amdgcn_mfma_f32_16x16x32_f16(a0, c1, acc2[0][1], 0,0,0);
      acc2[1][0] = __builtin_amdgcn_mfma_f32_16x16x32_f16(a1, c0, acc2[1][0], 0,0,0);
      acc2[1][1] = __builtin_amdgcn_mfma_f32_16x16x32_f16(a1, c1, acc2[1][1], 0,0,0);
    }
  }
  #pragma unroll
  for (int in = 0; in < 2; ++in) {
    const int n = n0 + nb + in*16 + l16;
    const float bv1 = bias1 ? bias1[n] : 0.f;
    const float bv2 = (dual && bias2) ? bias2[n] : 0.f;
    #pragma unroll
    for (int im = 0; im < 2; ++im) {
      const int mrow = m0 + mb + im*16 + quad*4;
      floatx4 c = acc1[im][in];
      #pragma unroll
      for (int r2 = 0; r2 < 4; ++r2) C1[(size_t)(mrow + r2)*DD + n] = c[r2] + bv1;
      if (dual) {
        floatx4 c2 = acc2[im][in];
        #pragma unroll
        for (int r2 = 0; r2 < 4; ++r2) C2[(size_t)(mrow + r2)*DD + n] = c2[r2] + bv2;
      }
    }
  }
}

// ============================================================================
// Persistent recurrence, 16 WGs x 64 rows, M-split waves:
// wave w owns rows [wg*64 + w*16, +16) with FULL K=1024 -> the MFMA acc IS
// the final dot product (no cross-wave LDS reduce, 1 barrier/step).
// Protocol per wave: payload u64 stores -> vmcnt(0) -> flags[wg*4+wave]=t+1.
// Consumer: poll 64 wave-flags, then ONE batched 16-load comm read.
// hf/axs cross-step reuse is guarded by the poll itself (flag t+1 implies
// that wave finished step-t MFMA + epilogue reads).
// ============================================================================
__global__ __launch_bounds__(256, 1) void recurrence_kernel(
    const float* __restrict__ Rh_raw, const float* __restrict__ Rd_raw,
    const float* __restrict__ logh0, const float* __restrict__ signh0,
    float* __restrict__ dout, unsigned char* __restrict__ ws) {
  const int wg = blockIdx.x;            // 0..15
  const int i0 = wg * ROWS;             // 64 rows per WG
  const int tid = threadIdx.x;
  const int wave = tid >> 6, lane = tid & 63;
  const int quad = lane >> 4, l16 = lane & 15;

  float* out_ax = dout + OUT_OFF;     // ax aliased into 'out' region
  float* hlin   = dout + HLIN_OFF;    // ad aliased here (consumed per step)
  float* logh   = dout + LOGH_OFF;
  float* signh  = dout + SIGNH_OFF;
  const float* scales = (const float*)(ws + WS_SCALES);
  unsigned* comm = (unsigned*)(ws + WS_COMM);   // dwords: [2][8][512]
  int* flags = (int*)(ws + WS_FLAGS);           // int[64] = [wg][wave]

  __shared__ _Float16 hf[16*HFS];
  __shared__ float axs[512];                    // [b][64 local rows]
  __shared__ float ads[512];

  // zero pad batch rows 8..15 of hf (never re-written)
  for (int idx = tid; idx < 8*HFS; idx += 256) hf[8*HFS + idx] = (_Float16)0.f;

  // static A-fragments: rows (i0 + wave*16 + l16), full K in 32 slices of 32.
  // afv[ks][j] = R[row][ks*32 + quad*8 + j] * scale.  256 VGPRs total.
  const float sh = scales[0], sd = scales[1];
  half8 afv[32], afd[32];
  {
    const float* rv = Rh_raw + (size_t)(i0 + wave*16 + l16)*DD;
    const float* rd = Rd_raw + (size_t)(i0 + wave*16 + l16)*DD;
    #pragma unroll
    for (int ks = 0; ks < 32; ++ks) {
      const int kb = ks*32 + quad*8;
      float4 v0 = *(const float4*)(rv + kb);
      float4 v1 = *(const float4*)(rv + kb + 4);
      float4 d0 = *(const float4*)(rd + kb);
      float4 d1 = *(const float4*)(rd + kb + 4);
      half8 hv, hd;
      hv[0]=(_Float16)(v0.x*sh); hv[1]=(_Float16)(v0.y*sh); hv[2]=(_Float16)(v0.z*sh); hv[3]=(_Float16)(v0.w*sh);
      hv[4]=(_Float16)(v1.x*sh); hv[5]=(_Float16)(v1.y*sh); hv[6]=(_Float16)(v1.z*sh); hv[7]=(_Float16)(v1.w*sh);
      hd[0]=(_Float16)(d0.x*sd); hd[1]=(_Float16)(d0.y*sd); hd[2]=(_Float16)(d0.z*sd); hd[3]=(_Float16)(d0.w*sd);
      hd[4]=(_Float16)(d1.x*sd); hd[5]=(_Float16)(d1.y*sd); hd[6]=(_Float16)(d1.z*sd); hd[7]=(_Float16)(d1.w*sd);
      afv[ks] = hv; afd[ks] = hd;
    }
  }

  // epilogue identity (from C layout col=lane&15, row=(lane>>4)*4+reg):
  // batch b = l16 (active if <8); local rows r0..r0+3, r0 = wave*16+quad*4.
  const int b = l16;
  const bool act = (l16 < 8);
  const int r0 = wave*16 + quad*4;     // local row base (div by 4)
  const int ei0 = i0 + r0;             // global row base
  float hp[4] = {0.f,0.f,0.f,0.f};
  if (act) {
    #pragma unroll
    for (int rr = 0; rr < 4; ++rr)
      hp[rr] = signh0[b*DD + ei0 + rr] * expf(logh0[b*DD + ei0 + rr]);
  }

  __syncthreads();

  for (int t = 0; t < TSTEPS; ++t) {
    // phase 0: coalesced ax/ad prefetch into regs (overlaps the poll).
    // thread i -> (b = i>>6, local row = i&63), plus the same at i+256.
    float ax0, ax1, ad0, ad1;
    {
      const int pb = tid >> 6, pr = tid & 63;
      const size_t base = (size_t)(t*8 + pb)*DD + i0 + pr;
      ax0 = out_ax[base];
      ax1 = out_ax[base + 4*DD];
      ad0 = hlin[base];
      ad1 = hlin[base + 4*DD];
    }
    floatx4 av = {0.f,0.f,0.f,0.f}, ad2 = {0.f,0.f,0.f,0.f};
    if (t > 0) {
      // phase 1: poll 64 wave-flags (one coalesced 256B load per round)
      {
        unsigned long long mask;
        do {
          int fv = aload_i(flags + lane);
          mask = __ballot(fv >= t);
        } while (mask != ~0ull);
      }
      // phase 2: ONE batched comm read (ack-certified visible), then LDS fill
      {
        unsigned* src = comm + ((t-1)&1)*4096 + tid;
        unsigned rbuf[16];
        #pragma unroll
        for (int q = 0; q < 16; ++q) rbuf[q] = aload_u(src + q*256);
        #pragma unroll
        for (int q = 0; q < 16; ++q) {
          const int w = q*256 + tid;
          *(unsigned*)&hf[(w >> 9)*HFS + (w & 511)*2] = rbuf[q];
        }
      }
    }
    // stage ax/ad to LDS (read back in epilogue with same-address broadcast)
    axs[tid] = ax0; axs[tid + 256] = ax1;
    ads[tid] = ad0; ads[tid + 256] = ad1;
    __syncthreads();
    if (t > 0) {
      // phase 3: full-K MFMA; both matrices share the B-fragment
      #pragma unroll
      for (int ks = 0; ks < 32; ++ks) {
        half8 bfrag = *(const half8*)&hf[l16*HFS + ks*32 + quad*8];
        av  = __builtin_amdgcn_mfma_f32_16x16x32_f16(afv[ks], bfrag, av,  0, 0, 0);
        ad2 = __builtin_amdgcn_mfma_f32_16x16x32_f16(afd[ks], bfrag, ad2, 0, 0, 0);
      }
    }
    // phase 4: epilogue (4 rows per active lane) + publish + ack + flag
    float h4[4];
    if (act) {
      #pragma unroll
      for (int rr = 0; rr < 4; ++rr) {
        float v  = axs[b*64 + r0 + rr] + av[rr];
        float dd = ads[b*64 + r0 + rr] + ad2[rr];
        float cand  = tanhf(v);
        float delta = 1.f/(1.f + expf(-dd));
        float hn = (1.f - delta)*hp[rr] + delta*cand;
        hp[rr] = hn; h4[rr] = hn;
      }
      unsigned d0 = (unsigned)__half_as_ushort(__float2half(h4[0])) |
                    ((unsigned)__half_as_ushort(__float2half(h4[1])) << 16);
      unsigned d1 = (unsigned)__half_as_ushort(__float2half(h4[2])) |
                    ((unsigned)__half_as_ushort(__float2half(h4[3])) << 16);
      unsigned long long pl = ((unsigned long long)d1 << 32) | (unsigned long long)d0;
      astore_u64((unsigned long long*)(comm + (t&1)*4096 + b*512 + (ei0 >> 1)), pl);
    }
    waitcnt_vm0();                               // per-wave payload ack
    if (lane == 0) astore_i(flags + (wg<<2) + wave, t + 1);
    // phase 5: off-critical-path output stores (log/sign computed here too)
    if (act) {
      const size_t ob = (size_t)(t*8 + b)*DD + ei0;
      *(float4*)&hlin[ob] = *(float4*)h4;
      float4 lg, sg;
      lg.x = logf(fabsf(h4[0]) + 1e-12f); sg.x = (h4[0] >= 0.f) ? 1.f : -1.f;
      lg.y = logf(fabsf(h4[1]) + 1e-12f); sg.y = (h4[1] >= 0.f) ? 1.f : -1.f;
      lg.z = logf(fabsf(h4[2]) + 1e-12f); sg.z = (h4[2] >= 0.f) ? 1.f : -1.f;
      lg.w = logf(fabsf(h4[3]) + 1e-12f); sg.w = (h4[3] >= 0.f) ? 1.f : -1.f;
      const size_t ob2 = (size_t)((t+1)*8 + b)*DD + ei0;
      *(float4*)&logh[ob2] = lg;
      *(float4*)&signh[ob2] = sg;
    }
  }
}

// ============================================================================
// out = softmax(h over groups of 32) * silu(h @ W_out^T), element-wise rewrite.
// ============================================================================
__global__ __launch_bounds__(256) void out_epilogue(
    const float* __restrict__ hlin, float* __restrict__ y_out) {
  const int row = blockIdx.x;          // t*8+b
  const int tid = threadIdx.x;
  const float* h = hlin + (size_t)row*DD;
  float* yo = y_out + (size_t)row*DD;
  const int e = tid*4;
  float4 hv = *(const float4*)(h + e);
  float4 yv = *(const float4*)(yo + e);
  float m = fmaxf(fmaxf(hv.x,hv.y), fmaxf(hv.z,hv.w));
  #pragma unroll
  for (int off = 1; off < 8; off <<= 1) m = fmaxf(m, __shfl_xor(m, off));
  float e0 = expf(hv.x - m), e1 = expf(hv.y - m), e2 = expf(hv.z - m), e3 = expf(hv.w - m);
  float s = e0+e1+e2+e3;
  #pragma unroll
  for (int off = 1; off < 8; off <<= 1) s += __shfl_xor(s, off);
  float inv = 1.f/s;
  float4 o;
  o.x = e0*inv * (yv.x/(1.f+expf(-yv.x)));
  o.y = e1*inv * (yv.y/(1.f+expf(-yv.y)));
  o.z = e2*inv * (yv.z/(1.f+expf(-yv.z)));
  o.w = e3*inv * (yv.w/(1.f+expf(-yv.w)));
  *(float4*)(yo + e) = o;
}

__global__ __launch_bounds__(256) void init_rows(
    const float* __restrict__ lh0, const float* __restrict__ sh0, float* __restrict__ dout) {
  int idx = blockIdx.x*256 + threadIdx.x;   // 8192
  dout[LOGH_OFF + idx]  = lh0[idx];
  dout[SIGNH_OFF + idx] = sh0[idx];
}

extern "C" void kernel_launch(void* const* d_in, const int* in_sizes, int n_in,
                              void* d_out, int out_size, void* d_ws, size_t ws_size,
                              hipStream_t stream) {
  const float* x      = (const float*)d_in[0];
  const float* logh0  = (const float*)d_in[1];
  const float* signh0 = (const float*)d_in[2];
  const float* Rh_raw = (const float*)d_in[3];
  const float* Rx     = (const float*)d_in[4];
  const float* Rd_raw = (const float*)d_in[5];
  const float* Wdelta = (const float*)d_in[6];
  const float* Wout   = (const float*)d_in[7];
  const float* bvec   = (const float*)d_in[8];
  const float* bdelta = (const float*)d_in[9];
  const float* uh     = (const float*)d_in[10];
  const float* ud     = (const float*)d_in[11];
  float* out = (float*)d_out;
  unsigned char* ws = (unsigned char*)d_ws;

  hipMemsetAsync(ws, 0, 512, stream);   // scales/sumsq/flags/cnts
  spectral_kernel<<<128, 256, 0, stream>>>(Rh_raw, Rd_raw, uh, ud, ws);
  // ax -> out region, ad -> h_lin region (dead-aliased scratch)
  gemm_f16<<<dim3(16,128), 256, 0, stream>>>(x, Rx, Wdelta, bvec, bdelta,
                                             out + OUT_OFF, out + HLIN_OFF);
  init_rows<<<32, 256, 0, stream>>>(logh0, signh0, out);
  recurrence_kernel<<<NWG, 256, 0, stream>>>(Rh_raw, Rd_raw, logh0, signh0, out, ws);
  // Y = h_lin @ W_out^T -> out region (ax dead)
  gemm_f16<<<dim3(16,128), 256, 0, stream>>>(out + HLIN_OFF, Wout, nullptr, nullptr, nullptr,
                                             out + OUT_OFF, nullptr);
  out_epilogue<<<8192, 256, 0, stream>>>(out + HLIN_OFF, out + OUT_OFF);
}